// Round 1
// baseline (125.600 us; speedup 1.0000x reference)
//
#include <hip/hip_runtime.h>
#include <math.h>

// Problem constants
#define KD 256          // inner dim of every GEMM (X_DIM == HID == 256)
#define ND 256          // output cols (HID == Y_DIM == 256)
#define MROWS 1024      // N samples

constexpr int BT = 64;          // block tile (rows and cols)
constexpr int KT = 64;          // k tile
constexpr int LS = 68;          // LDS row stride in floats: 68*4=272 bytes, 16B aligned

// ---------------------------------------------------------------------------
// Column moments over j: momA[d] = sum_j (y^2+z^2), momB[d] = sum_j (y+z)
// 16 blocks x 256 threads; thread = column, block = 64-row chunk. Coalesced.
// momA/momB must be pre-zeroed (hipMemsetAsync in kernel_launch).
// ---------------------------------------------------------------------------
__global__ __launch_bounds__(256)
void moments_kernel(const float* __restrict__ y, const float* __restrict__ z,
                    float* __restrict__ momA, float* __restrict__ momB) {
    int col = threadIdx.x;
    int row0 = blockIdx.x * 64;
    float sA = 0.f, sB = 0.f;
    for (int j = 0; j < 64; j++) {
        float yv = y[(row0 + j) * 256 + col];
        float zv = z[(row0 + j) * 256 + col];
        sA += yv * yv + zv * zv;
        sB += yv + zv;
    }
    atomicAdd(&momA[col], sA);
    atomicAdd(&momB[col], sB);
}

// ---------------------------------------------------------------------------
// C = A @ B^T + bias, optional relu.  A: (1024,256) row-major, B: (256,256)
// row-major (so both are K-contiguous). blockIdx.z selects the mu/lv head.
// 64x64 tile, 256 threads, 4x4 micro-tile, float4 LDS reads.
// ---------------------------------------------------------------------------
template <bool RELU>
__global__ __launch_bounds__(256)
void gemm_tn(const float* __restrict__ A0, const float* __restrict__ A1,
             const float* __restrict__ B0, const float* __restrict__ B1,
             const float* __restrict__ bias0, const float* __restrict__ bias1,
             float* __restrict__ C0, float* __restrict__ C1) {
    const int z = blockIdx.z;
    const float* __restrict__ A = z ? A1 : A0;
    const float* __restrict__ B = z ? B1 : B0;
    const float* __restrict__ bias = z ? bias1 : bias0;
    float* __restrict__ C = z ? C1 : C0;

    const int rowBase = blockIdx.x * BT;
    const int colBase = blockIdx.y * BT;
    const int t = threadIdx.x;
    const int tx = t & 15;   // micro col group (16 x 4 cols = 64)
    const int ty = t >> 4;   // micro row group (16 x 4 rows = 64)

    __shared__ float As[KT][LS];  // As[k][m]  (transposed during staging)
    __shared__ float Bs[KT][LS];  // Bs[k][n]

    float acc[4][4] = {};

    for (int kt = 0; kt < KD; kt += KT) {
        // stage 64x64 tiles of A and B (transposing k to leading dim)
#pragma unroll
        for (int p = 0; p < 4; p++) {
            int idx = p * 256 + t;
            int r = idx >> 4;    // 0..63 row within tile
            int k4 = idx & 15;   // float4 index along k
            float4 av = *(const float4*)&A[(rowBase + r) * KD + kt + k4 * 4];
            float4 bv = *(const float4*)&B[(colBase + r) * KD + kt + k4 * 4];
            As[k4 * 4 + 0][r] = av.x; As[k4 * 4 + 1][r] = av.y;
            As[k4 * 4 + 2][r] = av.z; As[k4 * 4 + 3][r] = av.w;
            Bs[k4 * 4 + 0][r] = bv.x; Bs[k4 * 4 + 1][r] = bv.y;
            Bs[k4 * 4 + 2][r] = bv.z; Bs[k4 * 4 + 3][r] = bv.w;
        }
        __syncthreads();

#pragma unroll 16
        for (int k = 0; k < KT; k++) {
            float4 a4 = *(const float4*)&As[k][ty * 4];
            float4 b4 = *(const float4*)&Bs[k][tx * 4];
            float av[4] = {a4.x, a4.y, a4.z, a4.w};
            float bv[4] = {b4.x, b4.y, b4.z, b4.w};
#pragma unroll
            for (int i = 0; i < 4; i++)
#pragma unroll
                for (int j = 0; j < 4; j++)
                    acc[i][j] = fmaf(av[i], bv[j], acc[i][j]);
        }
        __syncthreads();
    }

    float4 bq = *(const float4*)&bias[colBase + tx * 4];
    float bb[4] = {bq.x, bq.y, bq.z, bq.w};
#pragma unroll
    for (int i = 0; i < 4; i++) {
        int row = rowBase + ty * 4 + i;
        float4 o;
        float v0 = acc[i][0] + bb[0];
        float v1 = acc[i][1] + bb[1];
        float v2 = acc[i][2] + bb[2];
        float v3 = acc[i][3] + bb[3];
        if (RELU) {
            v0 = fmaxf(v0, 0.f); v1 = fmaxf(v1, 0.f);
            v2 = fmaxf(v2, 0.f); v3 = fmaxf(v3, 0.f);
        }
        o.x = v0; o.y = v1; o.z = v2; o.w = v3;
        *(float4*)&C[row * ND + colBase + tx * 4] = o;
    }
}

// ---------------------------------------------------------------------------
// Epilogue: per row i, diff_i = sum_o iv*(M - (mu-y)^2 - (mu-z)^2),
// out += relu(diff_i)/N.  256 blocks x 4 rows, thread = output dim o.
// ---------------------------------------------------------------------------
__global__ __launch_bounds__(256)
void epilogue_kernel(const float* __restrict__ mu, const float* __restrict__ lvp,
                     const float* __restrict__ y, const float* __restrict__ z,
                     const float* __restrict__ momA, const float* __restrict__ momB,
                     float* __restrict__ out) {
    __shared__ float red[4];
    int t = threadIdx.x;
    int lane = t & 63, wave = t >> 6;
    int row0 = blockIdx.x * 4;
    float mA = momA[t] * (1.f / 1024.f);   // mean_j (y^2+z^2)
    float mB = momB[t] * (1.f / 1024.f);   // mean_j (y+z)
    float blockSum = 0.f;
    for (int r = 0; r < 4; r++) {
        int i = row0 + r;
        float m  = mu[i * 256 + t];
        float lv = tanhf(lvp[i * 256 + t]);
        float iv = 0.5f * expf(-lv);       // 1/(2*exp(logvar))
        float yv = y[i * 256 + t];
        float zv = z[i * 256 + t];
        float Mt = mA - 2.f * m * mB + 2.f * m * m;   // mean_j sq
        float dy = m - yv, dz = m - zv;
        float term = iv * (Mt - dy * dy - dz * dz);   // positive - negative
        // wave64 butterfly reduce
#pragma unroll
        for (int mask = 32; mask; mask >>= 1)
            term += __shfl_xor(term, mask, 64);
        if (lane == 0) red[wave] = term;
        __syncthreads();
        if (t == 0) {
            float rs = red[0] + red[1] + red[2] + red[3];
            blockSum += fmaxf(rs, 0.f);
        }
        __syncthreads();
    }
    if (t == 0) atomicAdd(out, blockSum * (1.f / 1024.f));
}

// ---------------------------------------------------------------------------
extern "C" void kernel_launch(void* const* d_in, const int* in_sizes, int n_in,
                              void* d_out, int out_size, void* d_ws, size_t ws_size,
                              hipStream_t stream) {
    const float* x   = (const float*)d_in[0];
    const float* y   = (const float*)d_in[1];
    const float* zs  = (const float*)d_in[2];
    const float* w1m = (const float*)d_in[3];
    const float* b1m = (const float*)d_in[4];
    const float* w2m = (const float*)d_in[5];
    const float* b2m = (const float*)d_in[6];
    const float* w1l = (const float*)d_in[7];
    const float* b1l = (const float*)d_in[8];
    const float* w2l = (const float*)d_in[9];
    const float* b2l = (const float*)d_in[10];
    float* out = (float*)d_out;

    char* ws = (char*)d_ws;
    float* momA = (float*)(ws);
    float* momB = (float*)(ws + 1024);
    float* h_mu = (float*)(ws + 4096);
    float* h_lv = (float*)(ws + 4096 + (1u << 20));
    float* muO  = (float*)(ws + 4096 + 2u * (1u << 20));
    float* lvO  = (float*)(ws + 4096 + 3u * (1u << 20));

    // ws is poisoned 0xAA before every timed launch; zero what we accumulate into
    hipMemsetAsync(ws, 0, 2048, stream);
    hipMemsetAsync(d_out, 0, sizeof(float), stream);

    moments_kernel<<<16, 256, 0, stream>>>(y, zs, momA, momB);
    gemm_tn<true ><<<dim3(16, 4, 2), 256, 0, stream>>>(x, x, w1m, w1l, b1m, b1l, h_mu, h_lv);
    gemm_tn<false><<<dim3(16, 4, 2), 256, 0, stream>>>(h_mu, h_lv, w2m, w2l, b2m, b2l, muO, lvO);
    epilogue_kernel<<<256, 256, 0, stream>>>(muO, lvO, y, zs, momA, momB, out);
}

// Round 2
// 119.074 us; speedup vs baseline: 1.0548x; 1.0548x over previous
//
#include <hip/hip_runtime.h>
#include <math.h>

// Problem constants: N=1024, X_DIM=HID=Y_DIM=256
#define KD 256          // inner dim of every GEMM
#define ND 256          // output cols
constexpr int BT = 64;  // block tile (rows and cols)
constexpr int KT = 64;  // k tile
constexpr int LS = 68;  // LDS row stride in floats (68*4=272 B, 16B aligned)

// ---------------------------------------------------------------------------
// 64x64 fp32 tile GEMM: C = A @ B^T + bias (A,B both K-contiguous row-major).
// 256 threads, 4x4 micro-tile, float4 LDS reads. Exact (absmax 0.0 in R0).
// ---------------------------------------------------------------------------
template <bool RELU>
__device__ __forceinline__ void gemm_tile(const float* __restrict__ A,
                                          const float* __restrict__ B,
                                          const float* __restrict__ bias,
                                          float* __restrict__ C,
                                          int rowBase, int colBase) {
    const int t = threadIdx.x;
    const int tx = t & 15;   // micro col group (16 x 4 cols = 64)
    const int ty = t >> 4;   // micro row group (16 x 4 rows = 64)

    __shared__ float As[KT][LS];  // As[k][m] (transposed during staging)
    __shared__ float Bs[KT][LS];  // Bs[k][n]

    float acc[4][4] = {};

    for (int kt = 0; kt < KD; kt += KT) {
#pragma unroll
        for (int p = 0; p < 4; p++) {
            int idx = p * 256 + t;
            int r = idx >> 4;    // 0..63 row within tile
            int k4 = idx & 15;   // float4 index along k
            float4 av = *(const float4*)&A[(rowBase + r) * KD + kt + k4 * 4];
            float4 bv = *(const float4*)&B[(colBase + r) * KD + kt + k4 * 4];
            As[k4 * 4 + 0][r] = av.x; As[k4 * 4 + 1][r] = av.y;
            As[k4 * 4 + 2][r] = av.z; As[k4 * 4 + 3][r] = av.w;
            Bs[k4 * 4 + 0][r] = bv.x; Bs[k4 * 4 + 1][r] = bv.y;
            Bs[k4 * 4 + 2][r] = bv.z; Bs[k4 * 4 + 3][r] = bv.w;
        }
        __syncthreads();

#pragma unroll 16
        for (int k = 0; k < KT; k++) {
            float4 a4 = *(const float4*)&As[k][ty * 4];
            float4 b4 = *(const float4*)&Bs[k][tx * 4];
            float av[4] = {a4.x, a4.y, a4.z, a4.w};
            float bv[4] = {b4.x, b4.y, b4.z, b4.w};
#pragma unroll
            for (int i = 0; i < 4; i++)
#pragma unroll
                for (int j = 0; j < 4; j++)
                    acc[i][j] = fmaf(av[i], bv[j], acc[i][j]);
        }
        __syncthreads();
    }

    float4 bq = *(const float4*)&bias[colBase + tx * 4];
    float bb[4] = {bq.x, bq.y, bq.z, bq.w};
#pragma unroll
    for (int i = 0; i < 4; i++) {
        int row = rowBase + ty * 4 + i;
        float4 o;
        float v0 = acc[i][0] + bb[0];
        float v1 = acc[i][1] + bb[1];
        float v2 = acc[i][2] + bb[2];
        float v3 = acc[i][3] + bb[3];
        if (RELU) {
            v0 = fmaxf(v0, 0.f); v1 = fmaxf(v1, 0.f);
            v2 = fmaxf(v2, 0.f); v3 = fmaxf(v3, 0.f);
        }
        o.x = v0; o.y = v1; o.z = v2; o.w = v3;
        *(float4*)&C[row * ND + colBase + tx * 4] = o;
    }
}

// ---------------------------------------------------------------------------
// K1: layer-1 GEMM (both heads, relu) fused with column-moment partials and
// the d_out zeroing. Flat grid of 144 blocks:
//   blocks [0,128): GEMM  (z = bid&1, rowTile = (bid>>1)>>2, colTile = (bid>>1)&3)
//   blocks [128,144): moment partials over 64-row chunks (direct store, no atomics)
// ---------------------------------------------------------------------------
__global__ __launch_bounds__(256)
void k1_layer1_moments(const float* __restrict__ x,
                       const float* __restrict__ w1m, const float* __restrict__ w1l,
                       const float* __restrict__ b1m, const float* __restrict__ b1l,
                       float* __restrict__ h_mu, float* __restrict__ h_lv,
                       const float* __restrict__ y, const float* __restrict__ z,
                       float* __restrict__ pA, float* __restrict__ pB,
                       float* __restrict__ out) {
    int bid = blockIdx.x;
    if (bid < 128) {
        int zz = bid & 1;
        int g = bid >> 1;
        int rowBase = (g >> 2) * BT;
        int colBase = (g & 3) * BT;
        gemm_tile<true>(x, zz ? w1l : w1m, zz ? b1l : b1m, zz ? h_lv : h_mu,
                        rowBase, colBase);
    } else {
        int m = bid - 128;               // 0..15, rows [m*64, m*64+64)
        int t = threadIdx.x;             // column
        float sA = 0.f, sB = 0.f;
        int base = m * 64 * 256 + t;
#pragma unroll 8
        for (int j = 0; j < 64; j++) {
            float yv = y[base + j * 256];
            float zv = z[base + j * 256];
            sA += yv * yv + zv * zv;
            sB += yv + zv;
        }
        pA[m * 256 + t] = sA;
        pB[m * 256 + t] = sB;
        if (m == 0 && t == 0) out[0] = 0.f;   // zero accumulator before K3
    }
}

// ---------------------------------------------------------------------------
// K2: layer-2 GEMM (both heads, no relu). 128 blocks, same decode.
// ---------------------------------------------------------------------------
__global__ __launch_bounds__(256)
void k2_layer2(const float* __restrict__ h_mu, const float* __restrict__ h_lv,
               const float* __restrict__ w2m, const float* __restrict__ w2l,
               const float* __restrict__ b2m, const float* __restrict__ b2l,
               float* __restrict__ muO, float* __restrict__ lvO) {
    int bid = blockIdx.x;
    int zz = bid & 1;
    int g = bid >> 1;
    int rowBase = (g >> 2) * BT;
    int colBase = (g & 3) * BT;
    gemm_tile<false>(zz ? h_lv : h_mu, zz ? w2l : w2m, zz ? b2l : b2m,
                     zz ? lvO : muO, rowBase, colBase);
}

// ---------------------------------------------------------------------------
// K3: epilogue. Reduces the 16 moment partials inline, then per row:
//   diff_i = sum_o iv*(M - (mu-y)^2 - (mu-z)^2),  out += relu(diff_i)/N.
// 256 blocks x 4 rows; thread = output dim.
// ---------------------------------------------------------------------------
__global__ __launch_bounds__(256)
void k3_epilogue(const float* __restrict__ mu, const float* __restrict__ lvp,
                 const float* __restrict__ y, const float* __restrict__ z,
                 const float* __restrict__ pA, const float* __restrict__ pB,
                 float* __restrict__ out) {
    __shared__ float red[4];
    int t = threadIdx.x;
    int lane = t & 63, wave = t >> 6;
    int row0 = blockIdx.x * 4;

    float mA = 0.f, mB = 0.f;
#pragma unroll
    for (int m = 0; m < 16; m++) {
        mA += pA[m * 256 + t];
        mB += pB[m * 256 + t];
    }
    mA *= (1.f / 1024.f);   // mean_j (y^2+z^2)
    mB *= (1.f / 1024.f);   // mean_j (y+z)

    float blockSum = 0.f;
    for (int r = 0; r < 4; r++) {
        int i = row0 + r;
        float m  = mu[i * 256 + t];
        float lv = tanhf(lvp[i * 256 + t]);
        float iv = 0.5f * expf(-lv);       // 1/(2*exp(logvar))
        float yv = y[i * 256 + t];
        float zv = z[i * 256 + t];
        float Mt = mA - 2.f * m * mB + 2.f * m * m;   // mean_j sq
        float dy = m - yv, dz = m - zv;
        float term = iv * (Mt - dy * dy - dz * dz);   // positive - negative
#pragma unroll
        for (int mask = 32; mask; mask >>= 1)
            term += __shfl_xor(term, mask, 64);
        if (lane == 0) red[wave] = term;
        __syncthreads();
        if (t == 0) {
            float rs = red[0] + red[1] + red[2] + red[3];
            blockSum += fmaxf(rs, 0.f);
        }
        __syncthreads();
    }
    if (t == 0) atomicAdd(out, blockSum * (1.f / 1024.f));
}

// ---------------------------------------------------------------------------
extern "C" void kernel_launch(void* const* d_in, const int* in_sizes, int n_in,
                              void* d_out, int out_size, void* d_ws, size_t ws_size,
                              hipStream_t stream) {
    const float* x   = (const float*)d_in[0];
    const float* y   = (const float*)d_in[1];
    const float* zs  = (const float*)d_in[2];
    const float* w1m = (const float*)d_in[3];
    const float* b1m = (const float*)d_in[4];
    const float* w2m = (const float*)d_in[5];
    const float* b2m = (const float*)d_in[6];
    const float* w1l = (const float*)d_in[7];
    const float* b1l = (const float*)d_in[8];
    const float* w2l = (const float*)d_in[9];
    const float* b2l = (const float*)d_in[10];
    float* out = (float*)d_out;

    char* ws = (char*)d_ws;
    float* pA   = (float*)(ws);                       // 16x256 f32 = 16 KB
    float* pB   = (float*)(ws + (16u << 10));         // 16 KB
    float* h_mu = (float*)(ws + (64u << 10));                     // 1 MB
    float* h_lv = (float*)(ws + (64u << 10) + 1u * (1u << 20));
    float* muO  = (float*)(ws + (64u << 10) + 2u * (1u << 20));
    float* lvO  = (float*)(ws + (64u << 10) + 3u * (1u << 20));

    k1_layer1_moments<<<144, 256, 0, stream>>>(x, w1m, w1l, b1m, b1l,
                                               h_mu, h_lv, y, zs, pA, pB, out);
    k2_layer2<<<128, 256, 0, stream>>>(h_mu, h_lv, w2m, w2l, b2m, b2l, muO, lvO);
    k3_epilogue<<<256, 256, 0, stream>>>(muO, lvO, y, zs, pA, pB, out);
}

// Round 3
// 105.712 us; speedup vs baseline: 1.1881x; 1.1264x over previous
//
#include <hip/hip_runtime.h>
#include <math.h>

// Problem constants: N=1024, X_DIM=HID=Y_DIM=256.
// Structure: 3 launches, split-K(x2) GEMMs so each GEMM dispatch has 256
// blocks (one per CU). ReLU/bias-combine is deferred into the consumer.
constexpr int BT = 64;  // block tile (rows and cols)
constexpr int KT = 64;  // k sub-tile
constexpr int LS = 68;  // LDS row stride in floats (68*4=272 B, 16B aligned)

// ---------------------------------------------------------------------------
// 64x64 fp32 tile GEMM over K range [k0, k0+128): C = opA(A) @ B^T (+bias).
// SUMRELU_A: A := relu(A0 + A1) elementwise (fused layer-1 activation).
// bias == nullptr -> no bias (non-zero K chunk).
// 256 threads, 4x4 micro-tile, float4 LDS reads.
// ---------------------------------------------------------------------------
template <bool SUMRELU_A>
__device__ __forceinline__ void gemm_tile_sk(const float* __restrict__ A0,
                                             const float* __restrict__ A1,
                                             const float* __restrict__ B,
                                             const float* __restrict__ bias,
                                             float* __restrict__ C,
                                             int rowBase, int colBase, int k0) {
    const int t = threadIdx.x;
    const int tx = t & 15;   // micro col group (16 x 4 cols = 64)
    const int ty = t >> 4;   // micro row group (16 x 4 rows = 64)

    __shared__ float As[KT][LS];  // As[k][m] (transposed during staging)
    __shared__ float Bs[KT][LS];  // Bs[k][n]

    float acc[4][4] = {};

    for (int kt = k0; kt < k0 + 128; kt += KT) {
#pragma unroll
        for (int p = 0; p < 4; p++) {
            int idx = p * 256 + t;
            int r = idx >> 4;    // 0..63 row within tile
            int k4 = idx & 15;   // float4 index along k
            int off = (rowBase + r) * 256 + kt + k4 * 4;
            float4 av = *(const float4*)&A0[off];
            if (SUMRELU_A) {
                float4 a1 = *(const float4*)&A1[off];
                av.x = fmaxf(av.x + a1.x, 0.f);
                av.y = fmaxf(av.y + a1.y, 0.f);
                av.z = fmaxf(av.z + a1.z, 0.f);
                av.w = fmaxf(av.w + a1.w, 0.f);
            }
            float4 bv = *(const float4*)&B[(colBase + r) * 256 + kt + k4 * 4];
            As[k4 * 4 + 0][r] = av.x; As[k4 * 4 + 1][r] = av.y;
            As[k4 * 4 + 2][r] = av.z; As[k4 * 4 + 3][r] = av.w;
            Bs[k4 * 4 + 0][r] = bv.x; Bs[k4 * 4 + 1][r] = bv.y;
            Bs[k4 * 4 + 2][r] = bv.z; Bs[k4 * 4 + 3][r] = bv.w;
        }
        __syncthreads();

#pragma unroll 16
        for (int k = 0; k < KT; k++) {
            float4 a4 = *(const float4*)&As[k][ty * 4];
            float4 b4 = *(const float4*)&Bs[k][tx * 4];
            float av[4] = {a4.x, a4.y, a4.z, a4.w};
            float bv[4] = {b4.x, b4.y, b4.z, b4.w};
#pragma unroll
            for (int i = 0; i < 4; i++)
#pragma unroll
                for (int j = 0; j < 4; j++)
                    acc[i][j] = fmaf(av[i], bv[j], acc[i][j]);
        }
        __syncthreads();
    }

    float bb[4] = {0.f, 0.f, 0.f, 0.f};
    if (bias) {
        float4 bq = *(const float4*)&bias[colBase + tx * 4];
        bb[0] = bq.x; bb[1] = bq.y; bb[2] = bq.z; bb[3] = bq.w;
    }
#pragma unroll
    for (int i = 0; i < 4; i++) {
        int row = rowBase + ty * 4 + i;
        float4 o;
        o.x = acc[i][0] + bb[0];
        o.y = acc[i][1] + bb[1];
        o.z = acc[i][2] + bb[2];
        o.w = acc[i][3] + bb[3];
        *(float4*)&C[row * 256 + colBase + tx * 4] = o;
    }
}

// Block decode for 256 split-K GEMM blocks:
//   chunk = bid&1, head = (bid>>1)&1, colTile = (bid>>2)&3, rowTile = bid>>4
#define DECODE_GEMM(bid, chunk, head, rowBase, colBase, k0) \
    int chunk = (bid) & 1;                                  \
    int head  = ((bid) >> 1) & 1;                           \
    int colBase = (((bid) >> 2) & 3) * BT;                  \
    int rowBase = ((bid) >> 4) * BT;                        \
    int k0 = chunk * 128;

// ---------------------------------------------------------------------------
// K1: layer-1 split-K GEMM (pre-activation, bias in chunk 0) + column-moment
// partials + d_out zeroing. 272 blocks: [0,256) GEMM, [256,272) moments.
// ---------------------------------------------------------------------------
__global__ __launch_bounds__(256)
void k1_layer1_moments(const float* __restrict__ x,
                       const float* __restrict__ w1m, const float* __restrict__ w1l,
                       const float* __restrict__ b1m, const float* __restrict__ b1l,
                       float* __restrict__ hm0, float* __restrict__ hm1,
                       float* __restrict__ hl0, float* __restrict__ hl1,
                       const float* __restrict__ y, const float* __restrict__ z,
                       float* __restrict__ pA, float* __restrict__ pB,
                       float* __restrict__ out) {
    int bid = blockIdx.x;
    if (bid < 256) {
        DECODE_GEMM(bid, chunk, head, rowBase, colBase, k0)
        const float* B = head ? w1l : w1m;
        const float* bias = chunk ? nullptr : (head ? b1l : b1m);
        float* C = head ? (chunk ? hl1 : hl0) : (chunk ? hm1 : hm0);
        gemm_tile_sk<false>(x, nullptr, B, bias, C, rowBase, colBase, k0);
    } else {
        int m = bid - 256;               // 0..15, rows [m*64, m*64+64)
        int t = threadIdx.x;             // column
        float sA = 0.f, sB = 0.f;
        int base = m * 64 * 256 + t;
#pragma unroll 8
        for (int j = 0; j < 64; j++) {
            float yv = y[base + j * 256];
            float zv = z[base + j * 256];
            sA += yv * yv + zv * zv;
            sB += yv + zv;
        }
        pA[m * 256 + t] = sA;
        pB[m * 256 + t] = sB;
        if (m == 0 && t == 0) out[0] = 0.f;   // zero accumulator before K3
    }
}

// ---------------------------------------------------------------------------
// K2: layer-2 split-K GEMM; A = relu(h0+h1) fused in staging. 256 blocks.
// ---------------------------------------------------------------------------
__global__ __launch_bounds__(256)
void k2_layer2(const float* __restrict__ hm0, const float* __restrict__ hm1,
               const float* __restrict__ hl0, const float* __restrict__ hl1,
               const float* __restrict__ w2m, const float* __restrict__ w2l,
               const float* __restrict__ b2m, const float* __restrict__ b2l,
               float* __restrict__ mu0, float* __restrict__ mu1,
               float* __restrict__ lv0, float* __restrict__ lv1) {
    int bid = blockIdx.x;
    DECODE_GEMM(bid, chunk, head, rowBase, colBase, k0)
    const float* A0 = head ? hl0 : hm0;
    const float* A1 = head ? hl1 : hm1;
    const float* B = head ? w2l : w2m;
    const float* bias = chunk ? nullptr : (head ? b2l : b2m);
    float* C = head ? (chunk ? lv1 : lv0) : (chunk ? mu1 : mu0);
    gemm_tile_sk<true>(A0, A1, B, bias, C, rowBase, colBase, k0);
}

// ---------------------------------------------------------------------------
// K3: epilogue. mu = mu0+mu1, lv_pre = lv0+lv1; reduce 16 moment partials
// inline; per row i: diff = sum_o iv*(M - (mu-y)^2 - (mu-z)^2);
// out += relu(diff)/N. 256 blocks x 4 rows; thread = output dim.
// ---------------------------------------------------------------------------
__global__ __launch_bounds__(256)
void k3_epilogue(const float* __restrict__ mu0, const float* __restrict__ mu1,
                 const float* __restrict__ lv0, const float* __restrict__ lv1,
                 const float* __restrict__ y, const float* __restrict__ z,
                 const float* __restrict__ pA, const float* __restrict__ pB,
                 float* __restrict__ out) {
    __shared__ float red[4];
    int t = threadIdx.x;
    int lane = t & 63, wave = t >> 6;
    int row0 = blockIdx.x * 4;

    float mA = 0.f, mB = 0.f;
#pragma unroll
    for (int m = 0; m < 16; m++) {
        mA += pA[m * 256 + t];
        mB += pB[m * 256 + t];
    }
    mA *= (1.f / 1024.f);   // mean_j (y^2+z^2)
    mB *= (1.f / 1024.f);   // mean_j (y+z)

    float blockSum = 0.f;
    for (int r = 0; r < 4; r++) {
        int i = row0 + r;
        int o = i * 256 + t;
        float m  = mu0[o] + mu1[o];
        float lv = tanhf(lv0[o] + lv1[o]);
        float iv = 0.5f * expf(-lv);       // 1/(2*exp(logvar))
        float yv = y[o];
        float zv = z[o];
        float Mt = mA - 2.f * m * mB + 2.f * m * m;   // mean_j sq
        float dy = m - yv, dz = m - zv;
        float term = iv * (Mt - dy * dy - dz * dz);   // positive - negative
#pragma unroll
        for (int mask = 32; mask; mask >>= 1)
            term += __shfl_xor(term, mask, 64);
        if (lane == 0) red[wave] = term;
        __syncthreads();
        if (t == 0) {
            float rs = red[0] + red[1] + red[2] + red[3];
            blockSum += fmaxf(rs, 0.f);
        }
        __syncthreads();
    }
    if (t == 0) atomicAdd(out, blockSum * (1.f / 1024.f));
}

// ---------------------------------------------------------------------------
extern "C" void kernel_launch(void* const* d_in, const int* in_sizes, int n_in,
                              void* d_out, int out_size, void* d_ws, size_t ws_size,
                              hipStream_t stream) {
    const float* x   = (const float*)d_in[0];
    const float* y   = (const float*)d_in[1];
    const float* zs  = (const float*)d_in[2];
    const float* w1m = (const float*)d_in[3];
    const float* b1m = (const float*)d_in[4];
    const float* w2m = (const float*)d_in[5];
    const float* b2m = (const float*)d_in[6];
    const float* w1l = (const float*)d_in[7];
    const float* b1l = (const float*)d_in[8];
    const float* w2l = (const float*)d_in[9];
    const float* b2l = (const float*)d_in[10];
    float* out = (float*)d_out;

    char* ws = (char*)d_ws;
    float* pA  = (float*)(ws);                    // 16x256 f32 = 16 KB
    float* pB  = (float*)(ws + (16u << 10));      // 16 KB
    float* buf = (float*)(ws + (64u << 10));      // 8 x 1 MB fp32 buffers
    const unsigned MB = (1u << 20) / 4;           // floats per MB
    float* hm0 = buf + 0 * MB;
    float* hm1 = buf + 1 * MB;
    float* hl0 = buf + 2 * MB;
    float* hl1 = buf + 3 * MB;
    float* mu0 = buf + 4 * MB;
    float* mu1 = buf + 5 * MB;
    float* lv0 = buf + 6 * MB;
    float* lv1 = buf + 7 * MB;

    k1_layer1_moments<<<272, 256, 0, stream>>>(x, w1m, w1l, b1m, b1l,
                                               hm0, hm1, hl0, hl1,
                                               y, zs, pA, pB, out);
    k2_layer2<<<256, 256, 0, stream>>>(hm0, hm1, hl0, hl1,
                                       w2m, w2l, b2m, b2l,
                                       mu0, mu1, lv0, lv1);
    k3_epilogue<<<256, 256, 0, stream>>>(mu0, mu1, lv0, lv1,
                                         y, zs, pA, pB, out);
}